// Round 4
// baseline (592.259 us; speedup 1.0000x reference)
//
#include <hip/hip_runtime.h>
#include <stdint.h>

#define NH 16
#define DK 64
#define BB 16
#define SS 512
#define DM 1024
#define DFF 4096

typedef __attribute__((ext_vector_type(8))) __bf16 bf16x8;
typedef __attribute__((ext_vector_type(4))) float  float4v;

__device__ __forceinline__ unsigned short f2bf(float f) {
  union { float f; unsigned int u; } v; v.f = f;
  unsigned int u = v.u + 0x7fffu + ((v.u >> 16) & 1u);
  return (unsigned short)(u >> 16);
}

__device__ __forceinline__ void gld_lds16(const void* g, void* l) {
  __builtin_amdgcn_global_load_lds(
      (const __attribute__((address_space(1))) unsigned int*)g,
      (__attribute__((address_space(3))) unsigned int*)l, 16, 0, 0);
}

// ---------------- all weight transposes fused: fp32 [R][C] -> bf16 [C][R]
__global__ void transpose_all(const float* __restrict__ Wq, const float* __restrict__ Wk,
                              const float* __restrict__ Wv, const float* __restrict__ Wo,
                              const float* __restrict__ W1, const float* __restrict__ W2,
                              unsigned short* __restrict__ WqkvT, unsigned short* __restrict__ WoT,
                              unsigned short* __restrict__ W1T, unsigned short* __restrict__ W2T) {
  __shared__ float tile[32][33];
  int bid = blockIdx.x;
  const float* in; unsigned short* out; int R, C, tl;
  if (bid < 1024)      { in = Wq; out = WqkvT;            R = 1024; C = 1024; tl = bid; }
  else if (bid < 2048) { in = Wk; out = WqkvT + 1048576;  R = 1024; C = 1024; tl = bid - 1024; }
  else if (bid < 3072) { in = Wv; out = WqkvT + 2097152;  R = 1024; C = 1024; tl = bid - 2048; }
  else if (bid < 4096) { in = Wo; out = WoT;              R = 1024; C = 1024; tl = bid - 3072; }
  else if (bid < 8192) { in = W1; out = W1T;              R = 1024; C = 4096; tl = bid - 4096; }
  else                 { in = W2; out = W2T;              R = 4096; C = 1024; tl = bid - 8192; }
  int ntx = C >> 5;
  int c0 = (tl % ntx) * 32, r0 = (tl / ntx) * 32;
  int tx = threadIdx.x, ty = threadIdx.y;
  for (int j = ty; j < 32; j += 8)
    tile[j][tx] = in[(size_t)(r0 + j) * C + c0 + tx];
  __syncthreads();
  for (int j = ty; j < 32; j += 8)
    out[(size_t)(c0 + j) * R + r0 + tx] = f2bf(tile[tx][j]);
}

// ---------------- layernorm: fp32 [rows][1024] -> bf16
__global__ __launch_bounds__(256) void ln_bf16(const float* __restrict__ in,
                                               const float* __restrict__ g,
                                               const float* __restrict__ be,
                                               unsigned short* __restrict__ out) {
  int row = blockIdx.x, t = threadIdx.x;
  const float4* in4 = (const float4*)(in + (size_t)row * DM);
  float4 v = in4[t];
  float s  = v.x + v.y + v.z + v.w;
  float s2 = v.x * v.x + v.y * v.y + v.z * v.z + v.w * v.w;
  for (int off = 1; off < 64; off <<= 1) { s += __shfl_xor(s, off); s2 += __shfl_xor(s2, off); }
  __shared__ float rs[4], rs2[4];
  int wave = t >> 6;
  if ((t & 63) == 0) { rs[wave] = s; rs2[wave] = s2; }
  __syncthreads();
  s  = rs[0] + rs[1] + rs[2] + rs[3];
  s2 = rs2[0] + rs2[1] + rs2[2] + rs2[3];
  float mu = s * (1.f / DM);
  float var = s2 * (1.f / DM) - mu * mu;
  float rstd = rsqrtf(var + 1e-5f);
  float4 gv = ((const float4*)g)[t];
  float4 bv = ((const float4*)be)[t];
  unsigned short o0 = f2bf((v.x - mu) * rstd * gv.x + bv.x);
  unsigned short o1 = f2bf((v.y - mu) * rstd * gv.y + bv.y);
  unsigned short o2 = f2bf((v.z - mu) * rstd * gv.z + bv.z);
  unsigned short o3 = f2bf((v.w - mu) * rstd * gv.w + bv.w);
  uint2 pk; pk.x = o0 | ((unsigned)o1 << 16); pk.y = o2 | ((unsigned)o3 << 16);
  *(uint2*)(out + (size_t)row * DM + t * 4) = pk;
}

// ---------------- GEMM C[M,N] = A[M,K] * Bt[N,K]^T, m97 structure, 128x128 tile
// LDS granule swizzle: slot g^((row>>1)&3) -> fragment reads 2-way = free.
// SPLITK: blockIdx.z selects K-half; epilogue uses fp32 atomicAdd into a
// pre-zeroed buffer (keeps per-block MFMA:staging ratio, doubles TLP for the
// grid-limited N=1024 shapes -- R3 showed shrinking the tile instead regresses).
// MODE 0: QKV scatter (SPLITK=1)
// MODE 1: atomicAdd(outf, v [+ resid on z==0])            (Wo)
// MODE 2: outb = bf16(relu(acc+bias)) (SPLITK=1)          (FFN1)
// MODE 3: atomicAdd(outf, v [+ resid + bias on z==0])     (FFN2)
template <int MODE, int SPLITK>
__global__ __launch_bounds__(256, 2)
void gemm_bt(const unsigned short* __restrict__ A, const unsigned short* __restrict__ Bt,
             int M, int N, int K,
             const float* __restrict__ bias, const float* __restrict__ resid,
             float* __restrict__ outf, unsigned short* __restrict__ outb,
             unsigned short* __restrict__ qo, unsigned short* __restrict__ ko,
             unsigned short* __restrict__ vo) {
  __shared__ __align__(16) unsigned short As[128 * 32];
  __shared__ __align__(16) unsigned short Bs[128 * 32];
  const int t = threadIdx.x, lane = t & 63, wave = t >> 6;
  const int lc = lane & 15, lr = lane >> 4;
  const int wm = wave >> 1, wn = wave & 1;

  // group-major (GM=8) block swizzle: L2 pins one M-band, streams N
  const int nbn = gridDim.x;
  int pid = blockIdx.y * nbn + blockIdx.x;
  int nig = nbn << 3;
  int gid = pid / nig;
  int loc = pid - gid * nig;
  const int rowblk = (gid * 8 + (loc & 7)) * 128;
  const int colblk = (loc >> 3) * 128;

  float4v acc[4][4];
#pragma unroll
  for (int i = 0; i < 4; i++)
#pragma unroll
    for (int j = 0; j < 4; j++) acc[i][j] = (float4v)0.f;

  const int r0 = t >> 2;                      // row within 64-row chunk
  const int sg = ((t & 3) ^ ((r0 >> 1) & 3)); // swizzled source granule
  const int ldsoff = r0 * 32 + (t & 3) * 8;   // lane-contiguous dst
  const int goff = sg * 8;

  const int kbeg = (SPLITK > 1) ? blockIdx.z * (K / SPLITK) : 0;
  const int kend = kbeg + K / SPLITK;

  for (int k0 = kbeg; k0 < kend; k0 += 32) {
#pragma unroll
    for (int c = 0; c < 2; c++) {
      gld_lds16(A  + (size_t)(rowblk + c * 64 + r0) * K + k0 + goff, &As[c * 2048 + ldsoff]);
      gld_lds16(Bt + (size_t)(colblk + c * 64 + r0) * K + k0 + goff, &Bs[c * 2048 + ldsoff]);
    }
    __syncthreads();
    bf16x8 af[4], bfr[4];
    const int slot = (lr ^ ((lc >> 1) & 3)) * 8;
#pragma unroll
    for (int mt = 0; mt < 4; mt++)
      af[mt] = *(const bf16x8*)&As[(wm * 64 + mt * 16 + lc) * 32 + slot];
#pragma unroll
    for (int nt = 0; nt < 4; nt++)
      bfr[nt] = *(const bf16x8*)&Bs[(wn * 64 + nt * 16 + lc) * 32 + slot];
#pragma unroll
    for (int mt = 0; mt < 4; mt++)
#pragma unroll
      for (int nt = 0; nt < 4; nt++)
        acc[mt][nt] = __builtin_amdgcn_mfma_f32_16x16x32_bf16(af[mt], bfr[nt], acc[mt][nt], 0, 0, 0);
    __syncthreads();
  }

  const bool lead = (SPLITK == 1) || (blockIdx.z == 0);
#pragma unroll
  for (int mt = 0; mt < 4; mt++)
#pragma unroll
    for (int nt = 0; nt < 4; nt++)
#pragma unroll
      for (int r = 0; r < 4; r++) {
        int row = rowblk + wm * 64 + mt * 16 + lr * 4 + r;
        int col = colblk + wn * 64 + nt * 16 + lc;
        float v = acc[mt][nt][r];
        if (MODE == 0) {
          int b = row >> 9, s = row & 511;
          int f = col & 1023, h = f >> 6, d = f & 63;
          if (col < 1024)
            qo[(((size_t)b * NH + h) * SS + s) * DK + d] = f2bf(v);
          else if (col < 2048)
            ko[(((size_t)b * NH + h) * SS + s) * DK + d] = f2bf(v);
          else
            vo[(((size_t)b * NH + h) * DK + d) * SS + s] = f2bf(v);
        } else if (MODE == 1) {
          float add = v;
          if (lead) add += resid[(size_t)row * N + col];
          atomicAdd(&outf[(size_t)row * N + col], add);
        } else if (MODE == 2) {
          outb[(size_t)row * N + col] = f2bf(fmaxf(v + bias[col], 0.f));
        } else {
          float add = v;
          if (lead) add += resid[(size_t)row * N + col] + bias[col];
          atomicAdd(&outf[(size_t)row * N + col], add);
        }
      }
}

// ---------------- flash attention, causal, 1 block = (b, h, 128 q-rows)
// LDS swizzle: granule g stored at slot g^(row&7) -> fragment reads 2-way.
__global__ __launch_bounds__(256, 2)
void attn(const unsigned short* __restrict__ Qb, const unsigned short* __restrict__ Kb,
          const unsigned short* __restrict__ Vtb, unsigned short* __restrict__ Ob) {
  __shared__ __align__(16) unsigned short Qs[128 * 64];
  __shared__ __align__(16) unsigned short Ks[128 * 64];
  __shared__ __align__(16) unsigned short Vts[64 * 128];
  __shared__ __align__(16) unsigned short Ps[4 * 32 * 128];
  const int t = threadIdx.x, lane = t & 63, wave = t >> 6;
  const int lc = lane & 15, lr = lane >> 4;
  const int qt = blockIdx.x, h = blockIdx.y, b = blockIdx.z;
  const int Q0 = qt * 128;
  const size_t headQK = ((size_t)b * NH + h) * SS * DK;
  const size_t headV  = ((size_t)b * NH + h) * DK * SS;
  const float SCALE = 0.125f, L2E = 1.44269504f;

  const int qkg = ((t & 7) ^ ((t >> 3) & 7)) * 8;
  const int qkrow = (t >> 3) * 64;
  const int vg = ((t & 15) ^ ((t >> 4) & 7)) * 8;
  const int vrow = t >> 4;

  {
    const unsigned short* gq = Qb + headQK + (size_t)Q0 * DK;
#pragma unroll
    for (int c = 0; c < 4; c++)
      gld_lds16(gq + c * 2048 + qkrow + qkg, &Qs[c * 2048 + t * 8]);
  }

  float4v o_acc[2][4];
#pragma unroll
  for (int mt = 0; mt < 2; mt++)
#pragma unroll
    for (int nt = 0; nt < 4; nt++) o_acc[mt][nt] = (float4v)0.f;
  float m_i[2][4], l_i[2][4];
#pragma unroll
  for (int mt = 0; mt < 2; mt++)
#pragma unroll
    for (int r = 0; r < 4; r++) { m_i[mt][r] = -__builtin_inff(); l_i[mt][r] = 0.f; }

  for (int kt = 0; kt <= qt; kt++) {
    __syncthreads();
    const unsigned short* gk = Kb + headQK + (size_t)kt * 128 * DK;
#pragma unroll
    for (int c = 0; c < 4; c++)
      gld_lds16(gk + c * 2048 + qkrow + qkg, &Ks[c * 2048 + t * 8]);
#pragma unroll
    for (int c = 0; c < 4; c++) {
      int d = c * 16 + vrow;
      gld_lds16(Vtb + headV + (size_t)d * SS + kt * 128 + vg, &Vts[c * 2048 + t * 8]);
    }
    __syncthreads();

    float4v s[2][8];
#pragma unroll
    for (int mt = 0; mt < 2; mt++)
#pragma unroll
      for (int nt = 0; nt < 8; nt++) s[mt][nt] = (float4v)0.f;
#pragma unroll
    for (int kk = 0; kk < 2; kk++) {
      bf16x8 aq[2];
#pragma unroll
      for (int mt = 0; mt < 2; mt++) {
        int row = wave * 32 + mt * 16 + lc;
        aq[mt] = *(const bf16x8*)&Qs[row * 64 + (((kk * 4 + lr) ^ (lc & 7)) * 8)];
      }
#pragma unroll
      for (int nt = 0; nt < 8; nt++) {
        int row = nt * 16 + lc;
        bf16x8 bk = *(const bf16x8*)&Ks[row * 64 + (((kk * 4 + lr) ^ (lc & 7)) * 8)];
#pragma unroll
        for (int mt = 0; mt < 2; mt++)
          s[mt][nt] = __builtin_amdgcn_mfma_f32_16x16x32_bf16(aq[mt], bk, s[mt][nt], 0, 0, 0);
      }
    }
    const bool diag = (kt == qt);
#pragma unroll
    for (int mt = 0; mt < 2; mt++)
#pragma unroll
      for (int nt = 0; nt < 8; nt++)
#pragma unroll
        for (int r = 0; r < 4; r++) {
          float sv = s[mt][nt][r] * SCALE;
          if (diag && (nt * 16 + lc > wave * 32 + mt * 16 + lr * 4 + r)) sv = -__builtin_inff();
          s[mt][nt][r] = sv;
        }
    float alpha_a[2][4];
#pragma unroll
    for (int mt = 0; mt < 2; mt++)
#pragma unroll
      for (int r = 0; r < 4; r++) {
        float mx = -__builtin_inff();
#pragma unroll
        for (int nt = 0; nt < 8; nt++) mx = fmaxf(mx, s[mt][nt][r]);
        for (int off = 1; off < 16; off <<= 1) mx = fmaxf(mx, __shfl_xor(mx, off));
        float mnew = fmaxf(m_i[mt][r], mx);
        float alpha = exp2f((m_i[mt][r] - mnew) * L2E);
        m_i[mt][r] = mnew;
        float rsum = 0.f;
#pragma unroll
        for (int nt = 0; nt < 8; nt++) {
          float p = exp2f((s[mt][nt][r] - mnew) * L2E);
          s[mt][nt][r] = p;
          rsum += p;
        }
        for (int off = 1; off < 16; off <<= 1) rsum += __shfl_xor(rsum, off);
        l_i[mt][r] = l_i[mt][r] * alpha + rsum;
        alpha_a[mt][r] = alpha;
      }
#pragma unroll
    for (int mt = 0; mt < 2; mt++)
#pragma unroll
      for (int nt = 0; nt < 4; nt++)
#pragma unroll
        for (int r = 0; r < 4; r++) o_acc[mt][nt][r] *= alpha_a[mt][r];
    const int wbase = wave * 32 * 128;
#pragma unroll
    for (int mt = 0; mt < 2; mt++)
#pragma unroll
      for (int nt = 0; nt < 8; nt++) {
        int g = nt * 2 + (lc >> 3);
#pragma unroll
        for (int r = 0; r < 4; r++) {
          int rowp = mt * 16 + lr * 4 + r;
          Ps[wbase + rowp * 128 + ((g ^ (rowp & 7)) * 8) + (lc & 7)] = f2bf(s[mt][nt][r]);
        }
      }
#pragma unroll
    for (int kk = 0; kk < 4; kk++) {
      bf16x8 ap[2];
#pragma unroll
      for (int mt = 0; mt < 2; mt++) {
        int rowp = mt * 16 + lc;
        ap[mt] = *(const bf16x8*)&Ps[wbase + rowp * 128 + (((kk * 4 + lr) ^ (lc & 7)) * 8)];
      }
#pragma unroll
      for (int nt = 0; nt < 4; nt++) {
        int row = nt * 16 + lc;
        bf16x8 bv = *(const bf16x8*)&Vts[row * 128 + (((kk * 4 + lr) ^ (lc & 7)) * 8)];
#pragma unroll
        for (int mt = 0; mt < 2; mt++)
          o_acc[mt][nt] = __builtin_amdgcn_mfma_f32_16x16x32_bf16(ap[mt], bv, o_acc[mt][nt], 0, 0, 0);
      }
    }
  }
  float inv[2][4];
#pragma unroll
  for (int mt = 0; mt < 2; mt++)
#pragma unroll
    for (int r = 0; r < 4; r++) inv[mt][r] = 1.f / l_i[mt][r];
#pragma unroll
  for (int mt = 0; mt < 2; mt++)
#pragma unroll
    for (int nt = 0; nt < 4; nt++)
#pragma unroll
      for (int r = 0; r < 4; r++) {
        int sg2 = Q0 + wave * 32 + mt * 16 + lr * 4 + r;
        int col = h * DK + nt * 16 + lc;
        Ob[((size_t)b * SS + sg2) * DM + col] = f2bf(o_acc[mt][nt][r] * inv[mt][r]);
      }
}

extern "C" void kernel_launch(void* const* d_in, const int* in_sizes, int n_in,
                              void* d_out, int out_size, void* d_ws, size_t ws_size,
                              hipStream_t stream) {
  const float* x  = (const float*)d_in[0];
  const float* Wq = (const float*)d_in[1];
  const float* Wk = (const float*)d_in[2];
  const float* Wv = (const float*)d_in[3];
  const float* Wo = (const float*)d_in[4];
  const float* W1 = (const float*)d_in[5];
  const float* b1 = (const float*)d_in[6];
  const float* W2 = (const float*)d_in[7];
  const float* b2 = (const float*)d_in[8];
  const float* g1 = (const float*)d_in[9];
  const float* be1 = (const float*)d_in[10];
  const float* g2 = (const float*)d_in[11];
  const float* be2 = (const float*)d_in[12];

  char* ws = (char*)d_ws;
  unsigned short* WqkvT = (unsigned short*)(ws);                 // 6 MB
  unsigned short* WoT   = (unsigned short*)(ws + 6291456);       // 2 MB
  unsigned short* W1T   = (unsigned short*)(ws + 8388608);       // 8 MB
  unsigned short* W2T   = (unsigned short*)(ws + 16777216);      // 8 MB
  unsigned short* hbuf  = (unsigned short*)(ws + 25165824);      // 16 MB
  unsigned short* Qb    = (unsigned short*)(ws + 41943040);      // 16 MB
  unsigned short* Kb    = (unsigned short*)(ws + 58720256);      // 16 MB
  unsigned short* Vtb   = (unsigned short*)(ws + 75497472);      // 16 MB
  unsigned short* attnO = (unsigned short*)(ws + 92274688);      // 16 MB
  float*          x1    = (float*)(ws + 109051904);              // 32 MB
  unsigned short* ffn1  = (unsigned short*)(ws + 41943040);      // 64 MB, aliases Qb..attnO (dead)

  // zero the two split-K atomic accumulators (re-poisoned to 0xAA each call)
  hipMemsetAsync(x1, 0, 33554432, stream);
  hipMemsetAsync(d_out, 0, 33554432, stream);

  transpose_all<<<12288, dim3(32, 8), 0, stream>>>(Wq, Wk, Wv, Wo, W1, W2,
                                                   WqkvT, WoT, W1T, W2T);

  ln_bf16<<<8192, 256, 0, stream>>>(x, g1, be1, hbuf);

  gemm_bt<0, 1><<<dim3(24, 64), 256, 0, stream>>>(hbuf, WqkvT, 8192, 3072, 1024,
      nullptr, nullptr, nullptr, nullptr, Qb, Kb, Vtb);

  attn<<<dim3(4, NH, BB), 256, 0, stream>>>(Qb, Kb, Vtb, attnO);

  // x1 = x + attnO @ Wo   (split-K=2, atomic epilogue, x folded in on z==0)
  gemm_bt<1, 2><<<dim3(8, 64, 2), 256, 0, stream>>>(attnO, WoT, 8192, 1024, 1024,
      nullptr, x, x1, nullptr, nullptr, nullptr, nullptr);

  ln_bf16<<<8192, 256, 0, stream>>>(x1, g2, be2, hbuf);

  gemm_bt<2, 1><<<dim3(32, 64), 256, 0, stream>>>(hbuf, W1T, 8192, 4096, 1024,
      b1, nullptr, nullptr, ffn1, nullptr, nullptr, nullptr);

  // out = x1 + ffn1 @ W2 + b2   (split-K=2, atomic epilogue)
  gemm_bt<3, 2><<<dim3(8, 64, 2), 256, 0, stream>>>(ffn1, W2T, 8192, 1024, 4096,
      b2, x1, (float*)d_out, nullptr, nullptr, nullptr, nullptr);
}

// Round 5
// 487.439 us; speedup vs baseline: 1.2150x; 1.2150x over previous
//
#include <hip/hip_runtime.h>
#include <stdint.h>

#define NH 16
#define DK 64
#define BB 16
#define SS 512
#define DM 1024
#define DFF 4096

typedef __attribute__((ext_vector_type(8))) __bf16 bf16x8;
typedef __attribute__((ext_vector_type(4))) float  float4v;

__device__ __forceinline__ unsigned short f2bf(float f) {
  union { float f; unsigned int u; } v; v.f = f;
  unsigned int u = v.u + 0x7fffu + ((v.u >> 16) & 1u);
  return (unsigned short)(u >> 16);
}

__device__ __forceinline__ void gld_lds16(const void* g, void* l) {
  __builtin_amdgcn_global_load_lds(
      (const __attribute__((address_space(1))) unsigned int*)g,
      (__attribute__((address_space(3))) unsigned int*)l, 16, 0, 0);
}

// ---------------- all weight transposes fused: fp32 [R][C] -> bf16 [C][R]
__global__ void transpose_all(const float* __restrict__ Wq, const float* __restrict__ Wk,
                              const float* __restrict__ Wv, const float* __restrict__ Wo,
                              const float* __restrict__ W1, const float* __restrict__ W2,
                              unsigned short* __restrict__ WqkvT, unsigned short* __restrict__ WoT,
                              unsigned short* __restrict__ W1T, unsigned short* __restrict__ W2T) {
  __shared__ float tile[32][33];
  int bid = blockIdx.x;
  const float* in; unsigned short* out; int R, C, tl;
  if (bid < 1024)      { in = Wq; out = WqkvT;            R = 1024; C = 1024; tl = bid; }
  else if (bid < 2048) { in = Wk; out = WqkvT + 1048576;  R = 1024; C = 1024; tl = bid - 1024; }
  else if (bid < 3072) { in = Wv; out = WqkvT + 2097152;  R = 1024; C = 1024; tl = bid - 2048; }
  else if (bid < 4096) { in = Wo; out = WoT;              R = 1024; C = 1024; tl = bid - 3072; }
  else if (bid < 8192) { in = W1; out = W1T;              R = 1024; C = 4096; tl = bid - 4096; }
  else                 { in = W2; out = W2T;              R = 4096; C = 1024; tl = bid - 8192; }
  int ntx = C >> 5;
  int c0 = (tl % ntx) * 32, r0 = (tl / ntx) * 32;
  int tx = threadIdx.x, ty = threadIdx.y;
  for (int j = ty; j < 32; j += 8)
    tile[j][tx] = in[(size_t)(r0 + j) * C + c0 + tx];
  __syncthreads();
  for (int j = ty; j < 32; j += 8)
    out[(size_t)(c0 + j) * R + r0 + tx] = f2bf(tile[tx][j]);
}

// ---------------- layernorm: fp32 [rows][1024] -> bf16
__global__ __launch_bounds__(256) void ln_bf16(const float* __restrict__ in,
                                               const float* __restrict__ g,
                                               const float* __restrict__ be,
                                               unsigned short* __restrict__ out) {
  int row = blockIdx.x, t = threadIdx.x;
  const float4* in4 = (const float4*)(in + (size_t)row * DM);
  float4 v = in4[t];
  float s  = v.x + v.y + v.z + v.w;
  float s2 = v.x * v.x + v.y * v.y + v.z * v.z + v.w * v.w;
  for (int off = 1; off < 64; off <<= 1) { s += __shfl_xor(s, off); s2 += __shfl_xor(s2, off); }
  __shared__ float rs[4], rs2[4];
  int wave = t >> 6;
  if ((t & 63) == 0) { rs[wave] = s; rs2[wave] = s2; }
  __syncthreads();
  s  = rs[0] + rs[1] + rs[2] + rs[3];
  s2 = rs2[0] + rs2[1] + rs2[2] + rs2[3];
  float mu = s * (1.f / DM);
  float var = s2 * (1.f / DM) - mu * mu;
  float rstd = rsqrtf(var + 1e-5f);
  float4 gv = ((const float4*)g)[t];
  float4 bv = ((const float4*)be)[t];
  unsigned short o0 = f2bf((v.x - mu) * rstd * gv.x + bv.x);
  unsigned short o1 = f2bf((v.y - mu) * rstd * gv.y + bv.y);
  unsigned short o2 = f2bf((v.z - mu) * rstd * gv.z + bv.z);
  unsigned short o3 = f2bf((v.w - mu) * rstd * gv.w + bv.w);
  uint2 pk; pk.x = o0 | ((unsigned)o1 << 16); pk.y = o2 | ((unsigned)o3 << 16);
  *(uint2*)(out + (size_t)row * DM + t * 4) = pk;
}

// ---------------- GEMM C[M,N] = A[M,K] * Bt[N,K]^T, 128x128 tile, BK=64
// BK=64: 32 MFMAs/wave per barrier pair (2x the m97 BK=32 ratio) -> halves the
// structural barrier-drain stall. LDS 32 KB/block; occupancy still VGPR-bound
// at 4 blocks/CU so no loss (R3: smaller tile regressed; R4: split-K atomics
// regressed -- barrier amortization is the lever that is free on every axis).
// Row stride 128 B == 32 banks -> swizzle: granule g of row stored at slot
// g^(row&7); staging permutes the SOURCE granule so LDS dst stays
// lane-contiguous (same pattern as the attention Q/K tiles).
// MODE 0: QKV scatter  1: outf = resid + acc  2: outb = bf16(relu(acc+bias))
// MODE 3: outf = resid + acc + bias
template <int MODE>
__global__ __launch_bounds__(256, 2)
void gemm_bt(const unsigned short* __restrict__ A, const unsigned short* __restrict__ Bt,
             int M, int N, int K,
             const float* __restrict__ bias, const float* __restrict__ resid,
             float* __restrict__ outf, unsigned short* __restrict__ outb,
             unsigned short* __restrict__ qo, unsigned short* __restrict__ ko,
             unsigned short* __restrict__ vo) {
  __shared__ __align__(16) unsigned short As[128 * 64];
  __shared__ __align__(16) unsigned short Bs[128 * 64];
  const int t = threadIdx.x, lane = t & 63, wave = t >> 6;
  const int lc = lane & 15, lr = lane >> 4;
  const int wm = wave >> 1, wn = wave & 1;

  // group-major (GM=8) block swizzle: L2 pins one M-band, streams N
  const int nbn = gridDim.x;
  int pid = blockIdx.y * nbn + blockIdx.x;
  int nig = nbn << 3;
  int gid = pid / nig;
  int loc = pid - gid * nig;
  const int rowblk = (gid * 8 + (loc & 7)) * 128;
  const int colblk = (loc >> 3) * 128;

  float4v acc[4][4];
#pragma unroll
  for (int i = 0; i < 4; i++)
#pragma unroll
    for (int j = 0; j < 4; j++) acc[i][j] = (float4v)0.f;

  // staging: 256 threads x 16 B = 32 rows of 64 elems per chunk; 4 chunks each
  const int r0 = t >> 3;                      // row within 32-row chunk
  const int sg = (t & 7) ^ (r0 & 7);          // swizzled source granule
  const int goff = sg * 8;

  for (int k0 = 0; k0 < K; k0 += 64) {
#pragma unroll
    for (int c = 0; c < 4; c++) {
      gld_lds16(A  + (size_t)(rowblk + c * 32 + r0) * K + k0 + goff, &As[c * 2048 + t * 8]);
      gld_lds16(Bt + (size_t)(colblk + c * 32 + r0) * K + k0 + goff, &Bs[c * 2048 + t * 8]);
    }
    __syncthreads();
#pragma unroll
    for (int kk = 0; kk < 2; kk++) {
      const int slot = ((kk * 4 + lr) ^ (lc & 7)) * 8;
      bf16x8 af[4], bfr[4];
#pragma unroll
      for (int mt = 0; mt < 4; mt++)
        af[mt] = *(const bf16x8*)&As[(wm * 64 + mt * 16 + lc) * 64 + slot];
#pragma unroll
      for (int nt = 0; nt < 4; nt++)
        bfr[nt] = *(const bf16x8*)&Bs[(wn * 64 + nt * 16 + lc) * 64 + slot];
#pragma unroll
      for (int mt = 0; mt < 4; mt++)
#pragma unroll
        for (int nt = 0; nt < 4; nt++)
          acc[mt][nt] = __builtin_amdgcn_mfma_f32_16x16x32_bf16(af[mt], bfr[nt], acc[mt][nt], 0, 0, 0);
    }
    __syncthreads();
  }

#pragma unroll
  for (int mt = 0; mt < 4; mt++)
#pragma unroll
    for (int nt = 0; nt < 4; nt++)
#pragma unroll
      for (int r = 0; r < 4; r++) {
        int row = rowblk + wm * 64 + mt * 16 + lr * 4 + r;
        int col = colblk + wn * 64 + nt * 16 + lc;
        float v = acc[mt][nt][r];
        if (MODE == 0) {
          int b = row >> 9, s = row & 511;
          int f = col & 1023, h = f >> 6, d = f & 63;
          if (col < 1024)
            qo[(((size_t)b * NH + h) * SS + s) * DK + d] = f2bf(v);
          else if (col < 2048)
            ko[(((size_t)b * NH + h) * SS + s) * DK + d] = f2bf(v);
          else
            vo[(((size_t)b * NH + h) * DK + d) * SS + s] = f2bf(v);
        } else if (MODE == 1) {
          outf[(size_t)row * N + col] = resid[(size_t)row * N + col] + v;
        } else if (MODE == 2) {
          outb[(size_t)row * N + col] = f2bf(fmaxf(v + bias[col], 0.f));
        } else {
          outf[(size_t)row * N + col] = resid[(size_t)row * N + col] + v + bias[col];
        }
      }
}

// ---------------- flash attention, causal, 1 block = (b, h, 128 q-rows)
// LDS swizzle: granule g stored at slot g^(row&7) -> fragment reads 2-way.
__global__ __launch_bounds__(256, 2)
void attn(const unsigned short* __restrict__ Qb, const unsigned short* __restrict__ Kb,
          const unsigned short* __restrict__ Vtb, unsigned short* __restrict__ Ob) {
  __shared__ __align__(16) unsigned short Qs[128 * 64];
  __shared__ __align__(16) unsigned short Ks[128 * 64];
  __shared__ __align__(16) unsigned short Vts[64 * 128];
  __shared__ __align__(16) unsigned short Ps[4 * 32 * 128];
  const int t = threadIdx.x, lane = t & 63, wave = t >> 6;
  const int lc = lane & 15, lr = lane >> 4;
  const int qt = blockIdx.x, h = blockIdx.y, b = blockIdx.z;
  const int Q0 = qt * 128;
  const size_t headQK = ((size_t)b * NH + h) * SS * DK;
  const size_t headV  = ((size_t)b * NH + h) * DK * SS;
  const float SCALE = 0.125f, L2E = 1.44269504f;

  const int qkg = ((t & 7) ^ ((t >> 3) & 7)) * 8;
  const int qkrow = (t >> 3) * 64;
  const int vg = ((t & 15) ^ ((t >> 4) & 7)) * 8;
  const int vrow = t >> 4;

  {
    const unsigned short* gq = Qb + headQK + (size_t)Q0 * DK;
#pragma unroll
    for (int c = 0; c < 4; c++)
      gld_lds16(gq + c * 2048 + qkrow + qkg, &Qs[c * 2048 + t * 8]);
  }

  float4v o_acc[2][4];
#pragma unroll
  for (int mt = 0; mt < 2; mt++)
#pragma unroll
    for (int nt = 0; nt < 4; nt++) o_acc[mt][nt] = (float4v)0.f;
  float m_i[2][4], l_i[2][4];
#pragma unroll
  for (int mt = 0; mt < 2; mt++)
#pragma unroll
    for (int r = 0; r < 4; r++) { m_i[mt][r] = -__builtin_inff(); l_i[mt][r] = 0.f; }

  for (int kt = 0; kt <= qt; kt++) {
    __syncthreads();
    const unsigned short* gk = Kb + headQK + (size_t)kt * 128 * DK;
#pragma unroll
    for (int c = 0; c < 4; c++)
      gld_lds16(gk + c * 2048 + qkrow + qkg, &Ks[c * 2048 + t * 8]);
#pragma unroll
    for (int c = 0; c < 4; c++) {
      int d = c * 16 + vrow;
      gld_lds16(Vtb + headV + (size_t)d * SS + kt * 128 + vg, &Vts[c * 2048 + t * 8]);
    }
    __syncthreads();

    float4v s[2][8];
#pragma unroll
    for (int mt = 0; mt < 2; mt++)
#pragma unroll
      for (int nt = 0; nt < 8; nt++) s[mt][nt] = (float4v)0.f;
#pragma unroll
    for (int kk = 0; kk < 2; kk++) {
      bf16x8 aq[2];
#pragma unroll
      for (int mt = 0; mt < 2; mt++) {
        int row = wave * 32 + mt * 16 + lc;
        aq[mt] = *(const bf16x8*)&Qs[row * 64 + (((kk * 4 + lr) ^ (lc & 7)) * 8)];
      }
#pragma unroll
      for (int nt = 0; nt < 8; nt++) {
        int row = nt * 16 + lc;
        bf16x8 bk = *(const bf16x8*)&Ks[row * 64 + (((kk * 4 + lr) ^ (lc & 7)) * 8)];
#pragma unroll
        for (int mt = 0; mt < 2; mt++)
          s[mt][nt] = __builtin_amdgcn_mfma_f32_16x16x32_bf16(aq[mt], bk, s[mt][nt], 0, 0, 0);
      }
    }
    const bool diag = (kt == qt);
#pragma unroll
    for (int mt = 0; mt < 2; mt++)
#pragma unroll
      for (int nt = 0; nt < 8; nt++)
#pragma unroll
        for (int r = 0; r < 4; r++) {
          float sv = s[mt][nt][r] * SCALE;
          if (diag && (nt * 16 + lc > wave * 32 + mt * 16 + lr * 4 + r)) sv = -__builtin_inff();
          s[mt][nt][r] = sv;
        }
    float alpha_a[2][4];
#pragma unroll
    for (int mt = 0; mt < 2; mt++)
#pragma unroll
      for (int r = 0; r < 4; r++) {
        float mx = -__builtin_inff();
#pragma unroll
        for (int nt = 0; nt < 8; nt++) mx = fmaxf(mx, s[mt][nt][r]);
        for (int off = 1; off < 16; off <<= 1) mx = fmaxf(mx, __shfl_xor(mx, off));
        float mnew = fmaxf(m_i[mt][r], mx);
        float alpha = exp2f((m_i[mt][r] - mnew) * L2E);
        m_i[mt][r] = mnew;
        float rsum = 0.f;
#pragma unroll
        for (int nt = 0; nt < 8; nt++) {
          float p = exp2f((s[mt][nt][r] - mnew) * L2E);
          s[mt][nt][r] = p;
          rsum += p;
        }
        for (int off = 1; off < 16; off <<= 1) rsum += __shfl_xor(rsum, off);
        l_i[mt][r] = l_i[mt][r] * alpha + rsum;
        alpha_a[mt][r] = alpha;
      }
#pragma unroll
    for (int mt = 0; mt < 2; mt++)
#pragma unroll
      for (int nt = 0; nt < 4; nt++)
#pragma unroll
        for (int r = 0; r < 4; r++) o_acc[mt][nt][r] *= alpha_a[mt][r];
    const int wbase = wave * 32 * 128;
#pragma unroll
    for (int mt = 0; mt < 2; mt++)
#pragma unroll
      for (int nt = 0; nt < 8; nt++) {
        int g = nt * 2 + (lc >> 3);
#pragma unroll
        for (int r = 0; r < 4; r++) {
          int rowp = mt * 16 + lr * 4 + r;
          Ps[wbase + rowp * 128 + ((g ^ (rowp & 7)) * 8) + (lc & 7)] = f2bf(s[mt][nt][r]);
        }
      }
#pragma unroll
    for (int kk = 0; kk < 4; kk++) {
      bf16x8 ap[2];
#pragma unroll
      for (int mt = 0; mt < 2; mt++) {
        int rowp = mt * 16 + lc;
        ap[mt] = *(const bf16x8*)&Ps[wbase + rowp * 128 + (((kk * 4 + lr) ^ (lc & 7)) * 8)];
      }
#pragma unroll
      for (int nt = 0; nt < 4; nt++) {
        int row = nt * 16 + lc;
        bf16x8 bv = *(const bf16x8*)&Vts[row * 128 + (((kk * 4 + lr) ^ (lc & 7)) * 8)];
#pragma unroll
        for (int mt = 0; mt < 2; mt++)
          o_acc[mt][nt] = __builtin_amdgcn_mfma_f32_16x16x32_bf16(ap[mt], bv, o_acc[mt][nt], 0, 0, 0);
      }
    }
  }
  float inv[2][4];
#pragma unroll
  for (int mt = 0; mt < 2; mt++)
#pragma unroll
    for (int r = 0; r < 4; r++) inv[mt][r] = 1.f / l_i[mt][r];
#pragma unroll
  for (int mt = 0; mt < 2; mt++)
#pragma unroll
    for (int nt = 0; nt < 4; nt++)
#pragma unroll
      for (int r = 0; r < 4; r++) {
        int sg2 = Q0 + wave * 32 + mt * 16 + lr * 4 + r;
        int col = h * DK + nt * 16 + lc;
        Ob[((size_t)b * SS + sg2) * DM + col] = f2bf(o_acc[mt][nt][r] * inv[mt][r]);
      }
}

extern "C" void kernel_launch(void* const* d_in, const int* in_sizes, int n_in,
                              void* d_out, int out_size, void* d_ws, size_t ws_size,
                              hipStream_t stream) {
  const float* x  = (const float*)d_in[0];
  const float* Wq = (const float*)d_in[1];
  const float* Wk = (const float*)d_in[2];
  const float* Wv = (const float*)d_in[3];
  const float* Wo = (const float*)d_in[4];
  const float* W1 = (const float*)d_in[5];
  const float* b1 = (const float*)d_in[6];
  const float* W2 = (const float*)d_in[7];
  const float* b2 = (const float*)d_in[8];
  const float* g1 = (const float*)d_in[9];
  const float* be1 = (const float*)d_in[10];
  const float* g2 = (const float*)d_in[11];
  const float* be2 = (const float*)d_in[12];

  char* ws = (char*)d_ws;
  unsigned short* WqkvT = (unsigned short*)(ws);                 // 6 MB
  unsigned short* WoT   = (unsigned short*)(ws + 6291456);       // 2 MB
  unsigned short* W1T   = (unsigned short*)(ws + 8388608);       // 8 MB
  unsigned short* W2T   = (unsigned short*)(ws + 16777216);      // 8 MB
  unsigned short* hbuf  = (unsigned short*)(ws + 25165824);      // 16 MB
  unsigned short* Qb    = (unsigned short*)(ws + 41943040);      // 16 MB
  unsigned short* Kb    = (unsigned short*)(ws + 58720256);      // 16 MB
  unsigned short* Vtb   = (unsigned short*)(ws + 75497472);      // 16 MB
  unsigned short* attnO = (unsigned short*)(ws + 92274688);      // 16 MB
  float*          x1    = (float*)(ws + 109051904);              // 32 MB
  unsigned short* ffn1  = (unsigned short*)(ws + 41943040);      // 64 MB, aliases Qb..attnO (dead)

  transpose_all<<<12288, dim3(32, 8), 0, stream>>>(Wq, Wk, Wv, Wo, W1, W2,
                                                   WqkvT, WoT, W1T, W2T);

  ln_bf16<<<8192, 256, 0, stream>>>(x, g1, be1, hbuf);

  gemm_bt<0><<<dim3(24, 64), 256, 0, stream>>>(hbuf, WqkvT, 8192, 3072, 1024,
      nullptr, nullptr, nullptr, nullptr, Qb, Kb, Vtb);

  attn<<<dim3(4, NH, BB), 256, 0, stream>>>(Qb, Kb, Vtb, attnO);

  gemm_bt<1><<<dim3(8, 64), 256, 0, stream>>>(attnO, WoT, 8192, 1024, 1024,
      nullptr, x, x1, nullptr, nullptr, nullptr, nullptr);

  ln_bf16<<<8192, 256, 0, stream>>>(x1, g2, be2, hbuf);

  gemm_bt<2><<<dim3(32, 64), 256, 0, stream>>>(hbuf, W1T, 8192, 4096, 1024,
      b1, nullptr, nullptr, ffn1, nullptr, nullptr, nullptr);

  gemm_bt<3><<<dim3(8, 64), 256, 0, stream>>>(ffn1, W2T, 8192, 1024, 4096,
      b2, x1, (float*)d_out, nullptr, nullptr, nullptr, nullptr);
}

// Round 6
// 486.592 us; speedup vs baseline: 1.2172x; 1.0017x over previous
//
#include <hip/hip_runtime.h>
#include <stdint.h>

#define NH 16
#define DK 64
#define BB 16
#define SS 512
#define DM 1024
#define DFF 4096

typedef __attribute__((ext_vector_type(8))) __bf16 bf16x8;
typedef __attribute__((ext_vector_type(4))) float  float4v;

__device__ __forceinline__ unsigned short f2bf(float f) {
  union { float f; unsigned int u; } v; v.f = f;
  unsigned int u = v.u + 0x7fffu + ((v.u >> 16) & 1u);
  return (unsigned short)(u >> 16);
}

__device__ __forceinline__ void gld_lds16(const void* g, void* l) {
  __builtin_amdgcn_global_load_lds(
      (const __attribute__((address_space(1))) unsigned int*)g,
      (__attribute__((address_space(3))) unsigned int*)l, 16, 0, 0);
}

// ---------------- all weight transposes fused: fp32 [R][C] -> bf16 [C][R]
__global__ void transpose_all(const float* __restrict__ Wq, const float* __restrict__ Wk,
                              const float* __restrict__ Wv, const float* __restrict__ Wo,
                              const float* __restrict__ W1, const float* __restrict__ W2,
                              unsigned short* __restrict__ WqkvT, unsigned short* __restrict__ WoT,
                              unsigned short* __restrict__ W1T, unsigned short* __restrict__ W2T) {
  __shared__ float tile[32][33];
  int bid = blockIdx.x;
  const float* in; unsigned short* out; int R, C, tl;
  if (bid < 1024)      { in = Wq; out = WqkvT;            R = 1024; C = 1024; tl = bid; }
  else if (bid < 2048) { in = Wk; out = WqkvT + 1048576;  R = 1024; C = 1024; tl = bid - 1024; }
  else if (bid < 3072) { in = Wv; out = WqkvT + 2097152;  R = 1024; C = 1024; tl = bid - 2048; }
  else if (bid < 4096) { in = Wo; out = WoT;              R = 1024; C = 1024; tl = bid - 3072; }
  else if (bid < 8192) { in = W1; out = W1T;              R = 1024; C = 4096; tl = bid - 4096; }
  else                 { in = W2; out = W2T;              R = 4096; C = 1024; tl = bid - 8192; }
  int ntx = C >> 5;
  int c0 = (tl % ntx) * 32, r0 = (tl / ntx) * 32;
  int tx = threadIdx.x, ty = threadIdx.y;
  for (int j = ty; j < 32; j += 8)
    tile[j][tx] = in[(size_t)(r0 + j) * C + c0 + tx];
  __syncthreads();
  for (int j = ty; j < 32; j += 8)
    out[(size_t)(c0 + j) * R + r0 + tx] = f2bf(tile[tx][j]);
}

// ---------------- layernorm: fp32 [rows][1024] -> bf16
__global__ __launch_bounds__(256) void ln_bf16(const float* __restrict__ in,
                                               const float* __restrict__ g,
                                               const float* __restrict__ be,
                                               unsigned short* __restrict__ out) {
  int row = blockIdx.x, t = threadIdx.x;
  const float4* in4 = (const float4*)(in + (size_t)row * DM);
  float4 v = in4[t];
  float s  = v.x + v.y + v.z + v.w;
  float s2 = v.x * v.x + v.y * v.y + v.z * v.z + v.w * v.w;
  for (int off = 1; off < 64; off <<= 1) { s += __shfl_xor(s, off); s2 += __shfl_xor(s2, off); }
  __shared__ float rs[4], rs2[4];
  int wave = t >> 6;
  if ((t & 63) == 0) { rs[wave] = s; rs2[wave] = s2; }
  __syncthreads();
  s  = rs[0] + rs[1] + rs[2] + rs[3];
  s2 = rs2[0] + rs2[1] + rs2[2] + rs2[3];
  float mu = s * (1.f / DM);
  float var = s2 * (1.f / DM) - mu * mu;
  float rstd = rsqrtf(var + 1e-5f);
  float4 gv = ((const float4*)g)[t];
  float4 bv = ((const float4*)be)[t];
  unsigned short o0 = f2bf((v.x - mu) * rstd * gv.x + bv.x);
  unsigned short o1 = f2bf((v.y - mu) * rstd * gv.y + bv.y);
  unsigned short o2 = f2bf((v.z - mu) * rstd * gv.z + bv.z);
  unsigned short o3 = f2bf((v.w - mu) * rstd * gv.w + bv.w);
  uint2 pk; pk.x = o0 | ((unsigned)o1 << 16); pk.y = o2 | ((unsigned)o3 << 16);
  *(uint2*)(out + (size_t)row * DM + t * 4) = pk;
}

// ---------------- GEMM C[M,N] = A[M,K] * Bt[N,K]^T, 128x128 tile, BK=64,
// double-buffered LDS with prefetch-after-barrier:
//   iter k: __syncthreads() (drains prefetch k issued last iter, which had a
//   full 32-MFMA compute phase to land) -> issue prefetch k+1 into alt buffer
//   -> compute on buffer k. One barrier per K-step (was 2), and the
//   vmcnt(0)-before-barrier no longer serializes staging against compute.
// LDS 64 KB -> 2 blocks/CU = what we measure anyway (R5: 20-27%), so free.
// Swizzle: granule g of row stored at slot g^(row&7) (stride 128 B == 32
// banks); staging permutes the SOURCE granule so LDS dst stays lane-contiguous.
// MODE 0: QKV scatter  1: outf = resid + acc  2: outb = bf16(relu(acc+bias))
// MODE 3: outf = resid + acc + bias
template <int MODE>
__global__ __launch_bounds__(256, 2)
void gemm_bt(const unsigned short* __restrict__ A, const unsigned short* __restrict__ Bt,
             int M, int N, int K,
             const float* __restrict__ bias, const float* __restrict__ resid,
             float* __restrict__ outf, unsigned short* __restrict__ outb,
             unsigned short* __restrict__ qo, unsigned short* __restrict__ ko,
             unsigned short* __restrict__ vo) {
  __shared__ __align__(16) unsigned short As[2][128 * 64];
  __shared__ __align__(16) unsigned short Bs[2][128 * 64];
  const int t = threadIdx.x, lane = t & 63, wave = t >> 6;
  const int lc = lane & 15, lr = lane >> 4;
  const int wm = wave >> 1, wn = wave & 1;

  // group-major (GM=8) block swizzle: L2 pins one M-band, streams N
  const int nbn = gridDim.x;
  int pid = blockIdx.y * nbn + blockIdx.x;
  int nig = nbn << 3;
  int gid = pid / nig;
  int loc = pid - gid * nig;
  const int rowblk = (gid * 8 + (loc & 7)) * 128;
  const int colblk = (loc >> 3) * 128;

  float4v acc[4][4];
#pragma unroll
  for (int i = 0; i < 4; i++)
#pragma unroll
    for (int j = 0; j < 4; j++) acc[i][j] = (float4v)0.f;

  // staging: 256 threads x 16 B = 32 rows of 64 elems per chunk; 4 chunks each
  const int r0 = t >> 3;                      // row within 32-row chunk
  const int goff = ((t & 7) ^ (r0 & 7)) * 8;  // swizzled source granule offset
  const unsigned short* Ab = A  + (size_t)(rowblk + r0) * K + goff;
  const unsigned short* Bb = Bt + (size_t)(colblk + r0) * K + goff;

  const int nk = K >> 6;

  // prologue: stage tile 0 into buffer 0
#pragma unroll
  for (int c = 0; c < 4; c++) {
    gld_lds16(Ab + (size_t)(c * 32) * K, &As[0][c * 2048 + t * 8]);
    gld_lds16(Bb + (size_t)(c * 32) * K, &Bs[0][c * 2048 + t * 8]);
  }

  for (int ki = 0; ki < nk; ki++) {
    __syncthreads();  // drains the in-flight prefetch for tile ki
    if (ki + 1 < nk) {
      const int kn = (ki + 1) << 6;
      const int nb = (ki + 1) & 1;
#pragma unroll
      for (int c = 0; c < 4; c++) {
        gld_lds16(Ab + (size_t)(c * 32) * K + kn, &As[nb][c * 2048 + t * 8]);
        gld_lds16(Bb + (size_t)(c * 32) * K + kn, &Bs[nb][c * 2048 + t * 8]);
      }
    }
    const unsigned short* as = As[ki & 1];
    const unsigned short* bs = Bs[ki & 1];
#pragma unroll
    for (int kk = 0; kk < 2; kk++) {
      const int slot = ((kk * 4 + lr) ^ (lc & 7)) * 8;
      bf16x8 af[4], bfr[4];
#pragma unroll
      for (int mt = 0; mt < 4; mt++)
        af[mt] = *(const bf16x8*)&as[(wm * 64 + mt * 16 + lc) * 64 + slot];
#pragma unroll
      for (int nt = 0; nt < 4; nt++)
        bfr[nt] = *(const bf16x8*)&bs[(wn * 64 + nt * 16 + lc) * 64 + slot];
#pragma unroll
      for (int mt = 0; mt < 4; mt++)
#pragma unroll
        for (int nt = 0; nt < 4; nt++)
          acc[mt][nt] = __builtin_amdgcn_mfma_f32_16x16x32_bf16(af[mt], bfr[nt], acc[mt][nt], 0, 0, 0);
    }
  }

#pragma unroll
  for (int mt = 0; mt < 4; mt++)
#pragma unroll
    for (int nt = 0; nt < 4; nt++)
#pragma unroll
      for (int r = 0; r < 4; r++) {
        int row = rowblk + wm * 64 + mt * 16 + lr * 4 + r;
        int col = colblk + wn * 64 + nt * 16 + lc;
        float v = acc[mt][nt][r];
        if (MODE == 0) {
          int b = row >> 9, s = row & 511;
          int f = col & 1023, h = f >> 6, d = f & 63;
          if (col < 1024)
            qo[(((size_t)b * NH + h) * SS + s) * DK + d] = f2bf(v);
          else if (col < 2048)
            ko[(((size_t)b * NH + h) * SS + s) * DK + d] = f2bf(v);
          else
            vo[(((size_t)b * NH + h) * DK + d) * SS + s] = f2bf(v);
        } else if (MODE == 1) {
          outf[(size_t)row * N + col] = resid[(size_t)row * N + col] + v;
        } else if (MODE == 2) {
          outb[(size_t)row * N + col] = f2bf(fmaxf(v + bias[col], 0.f));
        } else {
          outf[(size_t)row * N + col] = resid[(size_t)row * N + col] + v + bias[col];
        }
      }
}

// ---------------- flash attention, causal, 1 block = (b, h, 128 q-rows)
// LDS swizzle: granule g stored at slot g^(row&7) -> fragment reads 2-way.
__global__ __launch_bounds__(256, 2)
void attn(const unsigned short* __restrict__ Qb, const unsigned short* __restrict__ Kb,
          const unsigned short* __restrict__ Vtb, unsigned short* __restrict__ Ob) {
  __shared__ __align__(16) unsigned short Qs[128 * 64];
  __shared__ __align__(16) unsigned short Ks[128 * 64];
  __shared__ __align__(16) unsigned short Vts[64 * 128];
  __shared__ __align__(16) unsigned short Ps[4 * 32 * 128];
  const int t = threadIdx.x, lane = t & 63, wave = t >> 6;
  const int lc = lane & 15, lr = lane >> 4;
  const int qt = blockIdx.x, h = blockIdx.y, b = blockIdx.z;
  const int Q0 = qt * 128;
  const size_t headQK = ((size_t)b * NH + h) * SS * DK;
  const size_t headV  = ((size_t)b * NH + h) * DK * SS;
  const float SCALE = 0.125f, L2E = 1.44269504f;

  const int qkg = ((t & 7) ^ ((t >> 3) & 7)) * 8;
  const int qkrow = (t >> 3) * 64;
  const int vg = ((t & 15) ^ ((t >> 4) & 7)) * 8;
  const int vrow = t >> 4;

  {
    const unsigned short* gq = Qb + headQK + (size_t)Q0 * DK;
#pragma unroll
    for (int c = 0; c < 4; c++)
      gld_lds16(gq + c * 2048 + qkrow + qkg, &Qs[c * 2048 + t * 8]);
  }

  float4v o_acc[2][4];
#pragma unroll
  for (int mt = 0; mt < 2; mt++)
#pragma unroll
    for (int nt = 0; nt < 4; nt++) o_acc[mt][nt] = (float4v)0.f;
  float m_i[2][4], l_i[2][4];
#pragma unroll
  for (int mt = 0; mt < 2; mt++)
#pragma unroll
    for (int r = 0; r < 4; r++) { m_i[mt][r] = -__builtin_inff(); l_i[mt][r] = 0.f; }

  for (int kt = 0; kt <= qt; kt++) {
    __syncthreads();
    const unsigned short* gk = Kb + headQK + (size_t)kt * 128 * DK;
#pragma unroll
    for (int c = 0; c < 4; c++)
      gld_lds16(gk + c * 2048 + qkrow + qkg, &Ks[c * 2048 + t * 8]);
#pragma unroll
    for (int c = 0; c < 4; c++) {
      int d = c * 16 + vrow;
      gld_lds16(Vtb + headV + (size_t)d * SS + kt * 128 + vg, &Vts[c * 2048 + t * 8]);
    }
    __syncthreads();

    float4v s[2][8];
#pragma unroll
    for (int mt = 0; mt < 2; mt++)
#pragma unroll
      for (int nt = 0; nt < 8; nt++) s[mt][nt] = (float4v)0.f;
#pragma unroll
    for (int kk = 0; kk < 2; kk++) {
      bf16x8 aq[2];
#pragma unroll
      for (int mt = 0; mt < 2; mt++) {
        int row = wave * 32 + mt * 16 + lc;
        aq[mt] = *(const bf16x8*)&Qs[row * 64 + (((kk * 4 + lr) ^ (lc & 7)) * 8)];
      }
#pragma unroll
      for (int nt = 0; nt < 8; nt++) {
        int row = nt * 16 + lc;
        bf16x8 bk = *(const bf16x8*)&Ks[row * 64 + (((kk * 4 + lr) ^ (lc & 7)) * 8)];
#pragma unroll
        for (int mt = 0; mt < 2; mt++)
          s[mt][nt] = __builtin_amdgcn_mfma_f32_16x16x32_bf16(aq[mt], bk, s[mt][nt], 0, 0, 0);
      }
    }
    const bool diag = (kt == qt);
#pragma unroll
    for (int mt = 0; mt < 2; mt++)
#pragma unroll
      for (int nt = 0; nt < 8; nt++)
#pragma unroll
        for (int r = 0; r < 4; r++) {
          float sv = s[mt][nt][r] * SCALE;
          if (diag && (nt * 16 + lc > wave * 32 + mt * 16 + lr * 4 + r)) sv = -__builtin_inff();
          s[mt][nt][r] = sv;
        }
    float alpha_a[2][4];
#pragma unroll
    for (int mt = 0; mt < 2; mt++)
#pragma unroll
      for (int r = 0; r < 4; r++) {
        float mx = -__builtin_inff();
#pragma unroll
        for (int nt = 0; nt < 8; nt++) mx = fmaxf(mx, s[mt][nt][r]);
        for (int off = 1; off < 16; off <<= 1) mx = fmaxf(mx, __shfl_xor(mx, off));
        float mnew = fmaxf(m_i[mt][r], mx);
        float alpha = exp2f((m_i[mt][r] - mnew) * L2E);
        m_i[mt][r] = mnew;
        float rsum = 0.f;
#pragma unroll
        for (int nt = 0; nt < 8; nt++) {
          float p = exp2f((s[mt][nt][r] - mnew) * L2E);
          s[mt][nt][r] = p;
          rsum += p;
        }
        for (int off = 1; off < 16; off <<= 1) rsum += __shfl_xor(rsum, off);
        l_i[mt][r] = l_i[mt][r] * alpha + rsum;
        alpha_a[mt][r] = alpha;
      }
#pragma unroll
    for (int mt = 0; mt < 2; mt++)
#pragma unroll
      for (int nt = 0; nt < 4; nt++)
#pragma unroll
        for (int r = 0; r < 4; r++) o_acc[mt][nt][r] *= alpha_a[mt][r];
    const int wbase = wave * 32 * 128;
#pragma unroll
    for (int mt = 0; mt < 2; mt++)
#pragma unroll
      for (int nt = 0; nt < 8; nt++) {
        int g = nt * 2 + (lc >> 3);
#pragma unroll
        for (int r = 0; r < 4; r++) {
          int rowp = mt * 16 + lr * 4 + r;
          Ps[wbase + rowp * 128 + ((g ^ (rowp & 7)) * 8) + (lc & 7)] = f2bf(s[mt][nt][r]);
        }
      }
#pragma unroll
    for (int kk = 0; kk < 4; kk++) {
      bf16x8 ap[2];
#pragma unroll
      for (int mt = 0; mt < 2; mt++) {
        int rowp = mt * 16 + lc;
        ap[mt] = *(const bf16x8*)&Ps[wbase + rowp * 128 + (((kk * 4 + lr) ^ (lc & 7)) * 8)];
      }
#pragma unroll
      for (int nt = 0; nt < 4; nt++) {
        int row = nt * 16 + lc;
        bf16x8 bv = *(const bf16x8*)&Vts[row * 128 + (((kk * 4 + lr) ^ (lc & 7)) * 8)];
#pragma unroll
        for (int mt = 0; mt < 2; mt++)
          o_acc[mt][nt] = __builtin_amdgcn_mfma_f32_16x16x32_bf16(ap[mt], bv, o_acc[mt][nt], 0, 0, 0);
      }
    }
  }
  float inv[2][4];
#pragma unroll
  for (int mt = 0; mt < 2; mt++)
#pragma unroll
    for (int r = 0; r < 4; r++) inv[mt][r] = 1.f / l_i[mt][r];
#pragma unroll
  for (int mt = 0; mt < 2; mt++)
#pragma unroll
    for (int nt = 0; nt < 4; nt++)
#pragma unroll
      for (int r = 0; r < 4; r++) {
        int sg2 = Q0 + wave * 32 + mt * 16 + lr * 4 + r;
        int col = h * DK + nt * 16 + lc;
        Ob[((size_t)b * SS + sg2) * DM + col] = f2bf(o_acc[mt][nt][r] * inv[mt][r]);
      }
}

extern "C" void kernel_launch(void* const* d_in, const int* in_sizes, int n_in,
                              void* d_out, int out_size, void* d_ws, size_t ws_size,
                              hipStream_t stream) {
  const float* x  = (const float*)d_in[0];
  const float* Wq = (const float*)d_in[1];
  const float* Wk = (const float*)d_in[2];
  const float* Wv = (const float*)d_in[3];
  const float* Wo = (const float*)d_in[4];
  const float* W1 = (const float*)d_in[5];
  const float* b1 = (const float*)d_in[6];
  const float* W2 = (const float*)d_in[7];
  const float* b2 = (const float*)d_in[8];
  const float* g1 = (const float*)d_in[9];
  const float* be1 = (const float*)d_in[10];
  const float* g2 = (const float*)d_in[11];
  const float* be2 = (const float*)d_in[12];

  char* ws = (char*)d_ws;
  unsigned short* WqkvT = (unsigned short*)(ws);                 // 6 MB
  unsigned short* WoT   = (unsigned short*)(ws + 6291456);       // 2 MB
  unsigned short* W1T   = (unsigned short*)(ws + 8388608);       // 8 MB
  unsigned short* W2T   = (unsigned short*)(ws + 16777216);      // 8 MB
  unsigned short* hbuf  = (unsigned short*)(ws + 25165824);      // 16 MB
  unsigned short* Qb    = (unsigned short*)(ws + 41943040);      // 16 MB
  unsigned short* Kb    = (unsigned short*)(ws + 58720256);      // 16 MB
  unsigned short* Vtb   = (unsigned short*)(ws + 75497472);      // 16 MB
  unsigned short* attnO = (unsigned short*)(ws + 92274688);      // 16 MB
  float*          x1    = (float*)(ws + 109051904);              // 32 MB
  unsigned short* ffn1  = (unsigned short*)(ws + 41943040);      // 64 MB, aliases Qb..attnO (dead)

  transpose_all<<<12288, dim3(32, 8), 0, stream>>>(Wq, Wk, Wv, Wo, W1, W2,
                                                   WqkvT, WoT, W1T, W2T);

  ln_bf16<<<8192, 256, 0, stream>>>(x, g1, be1, hbuf);

  gemm_bt<0><<<dim3(24, 64), 256, 0, stream>>>(hbuf, WqkvT, 8192, 3072, 1024,
      nullptr, nullptr, nullptr, nullptr, Qb, Kb, Vtb);

  attn<<<dim3(4, NH, BB), 256, 0, stream>>>(Qb, Kb, Vtb, attnO);

  gemm_bt<1><<<dim3(8, 64), 256, 0, stream>>>(attnO, WoT, 8192, 1024, 1024,
      nullptr, x, x1, nullptr, nullptr, nullptr, nullptr);

  ln_bf16<<<8192, 256, 0, stream>>>(x1, g2, be2, hbuf);

  gemm_bt<2><<<dim3(32, 64), 256, 0, stream>>>(hbuf, W1T, 8192, 4096, 1024,
      b1, nullptr, nullptr, ffn1, nullptr, nullptr, nullptr);

  gemm_bt<3><<<dim3(8, 64), 256, 0, stream>>>(ffn1, W2T, 8192, 1024, 4096,
      b2, x1, (float*)d_out, nullptr, nullptr, nullptr, nullptr);
}

// Round 7
// 476.846 us; speedup vs baseline: 1.2420x; 1.0204x over previous
//
#include <hip/hip_runtime.h>
#include <stdint.h>

#define NH 16
#define DK 64
#define BB 16
#define SS 512
#define DM 1024
#define DFF 4096

typedef __attribute__((ext_vector_type(8))) __bf16 bf16x8;
typedef __attribute__((ext_vector_type(4))) float  float4v;

__device__ __forceinline__ unsigned short f2bf(float f) {
  union { float f; unsigned int u; } v; v.f = f;
  unsigned int u = v.u + 0x7fffu + ((v.u >> 16) & 1u);
  return (unsigned short)(u >> 16);
}

__device__ __forceinline__ void gld_lds16(const void* g, void* l) {
  __builtin_amdgcn_global_load_lds(
      (const __attribute__((address_space(1))) unsigned int*)g,
      (__attribute__((address_space(3))) unsigned int*)l, 16, 0, 0);
}

// ---------------- all weight transposes fused: fp32 [R][C] -> bf16 [C][R]
__global__ void transpose_all(const float* __restrict__ Wq, const float* __restrict__ Wk,
                              const float* __restrict__ Wv, const float* __restrict__ Wo,
                              const float* __restrict__ W1, const float* __restrict__ W2,
                              unsigned short* __restrict__ WqkvT, unsigned short* __restrict__ WoT,
                              unsigned short* __restrict__ W1T, unsigned short* __restrict__ W2T) {
  __shared__ float tile[32][33];
  int bid = blockIdx.x;
  const float* in; unsigned short* out; int R, C, tl;
  if (bid < 1024)      { in = Wq; out = WqkvT;            R = 1024; C = 1024; tl = bid; }
  else if (bid < 2048) { in = Wk; out = WqkvT + 1048576;  R = 1024; C = 1024; tl = bid - 1024; }
  else if (bid < 3072) { in = Wv; out = WqkvT + 2097152;  R = 1024; C = 1024; tl = bid - 2048; }
  else if (bid < 4096) { in = Wo; out = WoT;              R = 1024; C = 1024; tl = bid - 3072; }
  else if (bid < 8192) { in = W1; out = W1T;              R = 1024; C = 4096; tl = bid - 4096; }
  else                 { in = W2; out = W2T;              R = 4096; C = 1024; tl = bid - 8192; }
  int ntx = C >> 5;
  int c0 = (tl % ntx) * 32, r0 = (tl / ntx) * 32;
  int tx = threadIdx.x, ty = threadIdx.y;
  for (int j = ty; j < 32; j += 8)
    tile[j][tx] = in[(size_t)(r0 + j) * C + c0 + tx];
  __syncthreads();
  for (int j = ty; j < 32; j += 8)
    out[(size_t)(c0 + j) * R + r0 + tx] = f2bf(tile[tx][j]);
}

// ---------------- layernorm: fp32 [rows][1024] -> bf16
__global__ __launch_bounds__(256) void ln_bf16(const float* __restrict__ in,
                                               const float* __restrict__ g,
                                               const float* __restrict__ be,
                                               unsigned short* __restrict__ out) {
  int row = blockIdx.x, t = threadIdx.x;
  const float4* in4 = (const float4*)(in + (size_t)row * DM);
  float4 v = in4[t];
  float s  = v.x + v.y + v.z + v.w;
  float s2 = v.x * v.x + v.y * v.y + v.z * v.z + v.w * v.w;
  for (int off = 1; off < 64; off <<= 1) { s += __shfl_xor(s, off); s2 += __shfl_xor(s2, off); }
  __shared__ float rs[4], rs2[4];
  int wave = t >> 6;
  if ((t & 63) == 0) { rs[wave] = s; rs2[wave] = s2; }
  __syncthreads();
  s  = rs[0] + rs[1] + rs[2] + rs[3];
  s2 = rs2[0] + rs2[1] + rs2[2] + rs2[3];
  float mu = s * (1.f / DM);
  float var = s2 * (1.f / DM) - mu * mu;
  float rstd = rsqrtf(var + 1e-5f);
  float4 gv = ((const float4*)g)[t];
  float4 bv = ((const float4*)be)[t];
  unsigned short o0 = f2bf((v.x - mu) * rstd * gv.x + bv.x);
  unsigned short o1 = f2bf((v.y - mu) * rstd * gv.y + bv.y);
  unsigned short o2 = f2bf((v.z - mu) * rstd * gv.z + bv.z);
  unsigned short o3 = f2bf((v.w - mu) * rstd * gv.w + bv.w);
  uint2 pk; pk.x = o0 | ((unsigned)o1 << 16); pk.y = o2 | ((unsigned)o3 << 16);
  *(uint2*)(out + (size_t)row * DM + t * 4) = pk;
}

// ---------------- GEMM C[M,N] = A[M,K] * Bt[N,K]^T, 128x128 tile, BK=64
// R5 configuration -- the measured plateau for this K-loop shape (~840 TF).
// R6 post-mortem: explicit dbuf regressed (compute phase 640 cy < HBM 900 cy,
// prefetch can't hide inside one iteration; +VGPR, -L2 locality). Do not
// re-add dbuf/split-K/smaller tiles to this structure.
// Swizzle: granule g of row stored at slot g^(row&7) (stride 128 B == 32
// banks); staging permutes the SOURCE granule so LDS dst stays lane-contiguous.
// MODE 0: QKV scatter  1: outf = resid + acc  2: outb = bf16(relu(acc+bias))
// MODE 3: outf = resid + acc + bias
template <int MODE>
__global__ __launch_bounds__(256, 2)
void gemm_bt(const unsigned short* __restrict__ A, const unsigned short* __restrict__ Bt,
             int M, int N, int K,
             const float* __restrict__ bias, const float* __restrict__ resid,
             float* __restrict__ outf, unsigned short* __restrict__ outb,
             unsigned short* __restrict__ qo, unsigned short* __restrict__ ko,
             unsigned short* __restrict__ vo) {
  __shared__ __align__(16) unsigned short As[128 * 64];
  __shared__ __align__(16) unsigned short Bs[128 * 64];
  const int t = threadIdx.x, lane = t & 63, wave = t >> 6;
  const int lc = lane & 15, lr = lane >> 4;
  const int wm = wave >> 1, wn = wave & 1;

  // group-major (GM=8) block swizzle: L2 pins one M-band, streams N
  const int nbn = gridDim.x;
  int pid = blockIdx.y * nbn + blockIdx.x;
  int nig = nbn << 3;
  int gid = pid / nig;
  int loc = pid - gid * nig;
  const int rowblk = (gid * 8 + (loc & 7)) * 128;
  const int colblk = (loc >> 3) * 128;

  float4v acc[4][4];
#pragma unroll
  for (int i = 0; i < 4; i++)
#pragma unroll
    for (int j = 0; j < 4; j++) acc[i][j] = (float4v)0.f;

  // staging: 256 threads x 16 B = 32 rows of 64 elems per chunk; 4 chunks each
  const int r0 = t >> 3;                      // row within 32-row chunk
  const int sg = (t & 7) ^ (r0 & 7);          // swizzled source granule
  const int goff = sg * 8;

  for (int k0 = 0; k0 < K; k0 += 64) {
#pragma unroll
    for (int c = 0; c < 4; c++) {
      gld_lds16(A  + (size_t)(rowblk + c * 32 + r0) * K + k0 + goff, &As[c * 2048 + t * 8]);
      gld_lds16(Bt + (size_t)(colblk + c * 32 + r0) * K + k0 + goff, &Bs[c * 2048 + t * 8]);
    }
    __syncthreads();
#pragma unroll
    for (int kk = 0; kk < 2; kk++) {
      const int slot = ((kk * 4 + lr) ^ (lc & 7)) * 8;
      bf16x8 af[4], bfr[4];
#pragma unroll
      for (int mt = 0; mt < 4; mt++)
        af[mt] = *(const bf16x8*)&As[(wm * 64 + mt * 16 + lc) * 64 + slot];
#pragma unroll
      for (int nt = 0; nt < 4; nt++)
        bfr[nt] = *(const bf16x8*)&Bs[(wn * 64 + nt * 16 + lc) * 64 + slot];
#pragma unroll
      for (int mt = 0; mt < 4; mt++)
#pragma unroll
        for (int nt = 0; nt < 4; nt++)
          acc[mt][nt] = __builtin_amdgcn_mfma_f32_16x16x32_bf16(af[mt], bfr[nt], acc[mt][nt], 0, 0, 0);
    }
    __syncthreads();
  }

#pragma unroll
  for (int mt = 0; mt < 4; mt++)
#pragma unroll
    for (int nt = 0; nt < 4; nt++)
#pragma unroll
      for (int r = 0; r < 4; r++) {
        int row = rowblk + wm * 64 + mt * 16 + lr * 4 + r;
        int col = colblk + wn * 64 + nt * 16 + lc;
        float v = acc[mt][nt][r];
        if (MODE == 0) {
          int b = row >> 9, s = row & 511;
          int f = col & 1023, h = f >> 6, d = f & 63;
          if (col < 1024)
            qo[(((size_t)b * NH + h) * SS + s) * DK + d] = f2bf(v);
          else if (col < 2048)
            ko[(((size_t)b * NH + h) * SS + s) * DK + d] = f2bf(v);
          else
            vo[(((size_t)b * NH + h) * DK + d) * SS + s] = f2bf(v);
        } else if (MODE == 1) {
          outf[(size_t)row * N + col] = resid[(size_t)row * N + col] + v;
        } else if (MODE == 2) {
          outb[(size_t)row * N + col] = f2bf(fmaxf(v + bias[col], 0.f));
        } else {
          outf[(size_t)row * N + col] = resid[(size_t)row * N + col] + v + bias[col];
        }
      }
}

// ---------------- flash attention, causal.
// Load balance: block (p, h, b) processes q-tiles {p, 3-p} -> every block does
// exactly 5 K-tile iterations (was 1..4 per block, stragglers set the
// makespan). Grid 512 blocks = 2/CU, uniform.
// LDS swizzle: granule g stored at slot g^(row&7) -> fragment reads 2-way.
__global__ __launch_bounds__(256, 2)
void attn(const unsigned short* __restrict__ Qb, const unsigned short* __restrict__ Kb,
          const unsigned short* __restrict__ Vtb, unsigned short* __restrict__ Ob) {
  __shared__ __align__(16) unsigned short Qs[128 * 64];
  __shared__ __align__(16) unsigned short Ks[128 * 64];
  __shared__ __align__(16) unsigned short Vts[64 * 128];
  __shared__ __align__(16) unsigned short Ps[4 * 32 * 128];
  const int t = threadIdx.x, lane = t & 63, wave = t >> 6;
  const int lc = lane & 15, lr = lane >> 4;
  const int p = blockIdx.x, h = blockIdx.y, b = blockIdx.z;
  const size_t headQK = ((size_t)b * NH + h) * SS * DK;
  const size_t headV  = ((size_t)b * NH + h) * DK * SS;
  const float SCALE = 0.125f, L2E = 1.44269504f;

  const int qkg = ((t & 7) ^ ((t >> 3) & 7)) * 8;
  const int qkrow = (t >> 3) * 64;
  const int vg = ((t & 15) ^ ((t >> 4) & 7)) * 8;
  const int vrow = t >> 4;

  for (int pass = 0; pass < 2; pass++) {
    const int qt = pass == 0 ? p : 3 - p;
    const int Q0 = qt * 128;

    if (pass) __syncthreads();  // previous pass finished reading Qs
    {
      const unsigned short* gq = Qb + headQK + (size_t)Q0 * DK;
#pragma unroll
      for (int c = 0; c < 4; c++)
        gld_lds16(gq + c * 2048 + qkrow + qkg, &Qs[c * 2048 + t * 8]);
    }

    float4v o_acc[2][4];
#pragma unroll
    for (int mt = 0; mt < 2; mt++)
#pragma unroll
      for (int nt = 0; nt < 4; nt++) o_acc[mt][nt] = (float4v)0.f;
    float m_i[2][4], l_i[2][4];
#pragma unroll
    for (int mt = 0; mt < 2; mt++)
#pragma unroll
      for (int r = 0; r < 4; r++) { m_i[mt][r] = -__builtin_inff(); l_i[mt][r] = 0.f; }

    for (int kt = 0; kt <= qt; kt++) {
      __syncthreads();  // previous tile consumed; also drains Q staging
      const unsigned short* gk = Kb + headQK + (size_t)kt * 128 * DK;
#pragma unroll
      for (int c = 0; c < 4; c++)
        gld_lds16(gk + c * 2048 + qkrow + qkg, &Ks[c * 2048 + t * 8]);
#pragma unroll
      for (int c = 0; c < 4; c++) {
        int d = c * 16 + vrow;
        gld_lds16(Vtb + headV + (size_t)d * SS + kt * 128 + vg, &Vts[c * 2048 + t * 8]);
      }
      __syncthreads();  // staging complete

      float4v s[2][8];
#pragma unroll
      for (int mt = 0; mt < 2; mt++)
#pragma unroll
        for (int nt = 0; nt < 8; nt++) s[mt][nt] = (float4v)0.f;
#pragma unroll
      for (int kk = 0; kk < 2; kk++) {
        bf16x8 aq[2];
#pragma unroll
        for (int mt = 0; mt < 2; mt++) {
          int row = wave * 32 + mt * 16 + lc;
          aq[mt] = *(const bf16x8*)&Qs[row * 64 + (((kk * 4 + lr) ^ (lc & 7)) * 8)];
        }
#pragma unroll
        for (int nt = 0; nt < 8; nt++) {
          int row = nt * 16 + lc;
          bf16x8 bk = *(const bf16x8*)&Ks[row * 64 + (((kk * 4 + lr) ^ (lc & 7)) * 8)];
#pragma unroll
          for (int mt = 0; mt < 2; mt++)
            s[mt][nt] = __builtin_amdgcn_mfma_f32_16x16x32_bf16(aq[mt], bk, s[mt][nt], 0, 0, 0);
        }
      }
      const bool diag = (kt == qt);
#pragma unroll
      for (int mt = 0; mt < 2; mt++)
#pragma unroll
        for (int nt = 0; nt < 8; nt++)
#pragma unroll
          for (int r = 0; r < 4; r++) {
            float sv = s[mt][nt][r] * SCALE;
            if (diag && (nt * 16 + lc > wave * 32 + mt * 16 + lr * 4 + r)) sv = -__builtin_inff();
            s[mt][nt][r] = sv;
          }
      float alpha_a[2][4];
#pragma unroll
      for (int mt = 0; mt < 2; mt++)
#pragma unroll
        for (int r = 0; r < 4; r++) {
          float mx = -__builtin_inff();
#pragma unroll
          for (int nt = 0; nt < 8; nt++) mx = fmaxf(mx, s[mt][nt][r]);
          for (int off = 1; off < 16; off <<= 1) mx = fmaxf(mx, __shfl_xor(mx, off));
          float mnew = fmaxf(m_i[mt][r], mx);
          float alpha = exp2f((m_i[mt][r] - mnew) * L2E);
          m_i[mt][r] = mnew;
          float rsum = 0.f;
#pragma unroll
          for (int nt = 0; nt < 8; nt++) {
            float pe = exp2f((s[mt][nt][r] - mnew) * L2E);
            s[mt][nt][r] = pe;
            rsum += pe;
          }
          for (int off = 1; off < 16; off <<= 1) rsum += __shfl_xor(rsum, off);
          l_i[mt][r] = l_i[mt][r] * alpha + rsum;
          alpha_a[mt][r] = alpha;
        }
#pragma unroll
      for (int mt = 0; mt < 2; mt++)
#pragma unroll
        for (int nt = 0; nt < 4; nt++)
#pragma unroll
          for (int r = 0; r < 4; r++) o_acc[mt][nt][r] *= alpha_a[mt][r];
      const int wbase = wave * 32 * 128;
#pragma unroll
      for (int mt = 0; mt < 2; mt++)
#pragma unroll
        for (int nt = 0; nt < 8; nt++) {
          int g = nt * 2 + (lc >> 3);
#pragma unroll
          for (int r = 0; r < 4; r++) {
            int rowp = mt * 16 + lr * 4 + r;
            Ps[wbase + rowp * 128 + ((g ^ (rowp & 7)) * 8) + (lc & 7)] = f2bf(s[mt][nt][r]);
          }
        }
#pragma unroll
      for (int kk = 0; kk < 4; kk++) {
        bf16x8 ap[2];
#pragma unroll
        for (int mt = 0; mt < 2; mt++) {
          int rowp = mt * 16 + lc;
          ap[mt] = *(const bf16x8*)&Ps[wbase + rowp * 128 + (((kk * 4 + lr) ^ (lc & 7)) * 8)];
        }
#pragma unroll
        for (int nt = 0; nt < 4; nt++) {
          int row = nt * 16 + lc;
          bf16x8 bv = *(const bf16x8*)&Vts[row * 128 + (((kk * 4 + lr) ^ (lc & 7)) * 8)];
#pragma unroll
          for (int mt = 0; mt < 2; mt++)
            o_acc[mt][nt] = __builtin_amdgcn_mfma_f32_16x16x32_bf16(ap[mt], bv, o_acc[mt][nt], 0, 0, 0);
        }
      }
    }
    float inv[2][4];
#pragma unroll
    for (int mt = 0; mt < 2; mt++)
#pragma unroll
      for (int r = 0; r < 4; r++) inv[mt][r] = 1.f / l_i[mt][r];
#pragma unroll
    for (int mt = 0; mt < 2; mt++)
#pragma unroll
      for (int nt = 0; nt < 4; nt++)
#pragma unroll
        for (int r = 0; r < 4; r++) {
          int sg2 = Q0 + wave * 32 + mt * 16 + lr * 4 + r;
          int col = h * DK + nt * 16 + lc;
          Ob[((size_t)b * SS + sg2) * DM + col] = f2bf(o_acc[mt][nt][r] * inv[mt][r]);
        }
  }
}

extern "C" void kernel_launch(void* const* d_in, const int* in_sizes, int n_in,
                              void* d_out, int out_size, void* d_ws, size_t ws_size,
                              hipStream_t stream) {
  const float* x  = (const float*)d_in[0];
  const float* Wq = (const float*)d_in[1];
  const float* Wk = (const float*)d_in[2];
  const float* Wv = (const float*)d_in[3];
  const float* Wo = (const float*)d_in[4];
  const float* W1 = (const float*)d_in[5];
  const float* b1 = (const float*)d_in[6];
  const float* W2 = (const float*)d_in[7];
  const float* b2 = (const float*)d_in[8];
  const float* g1 = (const float*)d_in[9];
  const float* be1 = (const float*)d_in[10];
  const float* g2 = (const float*)d_in[11];
  const float* be2 = (const float*)d_in[12];

  char* ws = (char*)d_ws;
  unsigned short* WqkvT = (unsigned short*)(ws);                 // 6 MB
  unsigned short* WoT   = (unsigned short*)(ws + 6291456);       // 2 MB
  unsigned short* W1T   = (unsigned short*)(ws + 8388608);       // 8 MB
  unsigned short* W2T   = (unsigned short*)(ws + 16777216);      // 8 MB
  unsigned short* hbuf  = (unsigned short*)(ws + 25165824);      // 16 MB
  unsigned short* Qb    = (unsigned short*)(ws + 41943040);      // 16 MB
  unsigned short* Kb    = (unsigned short*)(ws + 58720256);      // 16 MB
  unsigned short* Vtb   = (unsigned short*)(ws + 75497472);      // 16 MB
  unsigned short* attnO = (unsigned short*)(ws + 92274688);      // 16 MB
  float*          x1    = (float*)(ws + 109051904);              // 32 MB
  unsigned short* ffn1  = (unsigned short*)(ws + 41943040);      // 64 MB, aliases Qb..attnO (dead)

  transpose_all<<<12288, dim3(32, 8), 0, stream>>>(Wq, Wk, Wv, Wo, W1, W2,
                                                   WqkvT, WoT, W1T, W2T);

  ln_bf16<<<8192, 256, 0, stream>>>(x, g1, be1, hbuf);

  gemm_bt<0><<<dim3(24, 64), 256, 0, stream>>>(hbuf, WqkvT, 8192, 3072, 1024,
      nullptr, nullptr, nullptr, nullptr, Qb, Kb, Vtb);

  attn<<<dim3(2, NH, BB), 256, 0, stream>>>(Qb, Kb, Vtb, attnO);

  gemm_bt<1><<<dim3(8, 64), 256, 0, stream>>>(attnO, WoT, 8192, 1024, 1024,
      nullptr, x, x1, nullptr, nullptr, nullptr, nullptr);

  ln_bf16<<<8192, 256, 0, stream>>>(x1, g2, be2, hbuf);

  gemm_bt<2><<<dim3(32, 64), 256, 0, stream>>>(hbuf, W1T, 8192, 4096, 1024,
      b1, nullptr, nullptr, ffn1, nullptr, nullptr, nullptr);

  gemm_bt<3><<<dim3(8, 64), 256, 0, stream>>>(ffn1, W2T, 8192, 1024, 4096,
      b2, x1, (float*)d_out, nullptr, nullptr, nullptr, nullptr);
}